// Round 3
// baseline (504.629 us; speedup 1.0000x reference)
//
#include <hip/hip_runtime.h>
#include <hip/hip_bf16.h>

// Problem constants
#define B_  128
#define T_  512
#define D_  400
#define NV  1024
#define NA  128

// Main-kernel tiling: split-T flash decoding.
// Block = (b, chunk); chunk = 64 t rows staged ONCE in LDS (53248 B -> 3 blocks/CU),
// then a barrier-free v-loop: 4 iters x (wave owns 64 v = 4 MFMA row-sets).
// LDS swizzle: 16B chunk c of row r stored at c ^ (r&7) for c<48 (verified round 1/2).
#define LDH   416          // bf16 row pitch (832 B = 52 chunks of 16 B)
#define NT    64           // t rows per chunk
#define NCH   8            // T_/NT

typedef __bf16 bf16_t;
typedef bf16_t bf16x8 __attribute__((ext_vector_type(8)));
typedef float  floatx4 __attribute__((ext_vector_type(4)));

__device__ inline float dot4(float4 a, float4 b) {
    return a.x * b.x + a.y * b.y + a.z * b.z + a.w * b.w;
}

// ---------------------------------------------------------------------------
// Kernel 1: hw[b,t] = H[b,t,:].W   (blocks [0,16384))
//           Cvb[v,:] = bf16(Cv[v,:]) padded to 416   (blocks [16384,16640))
// One wave per row in both halves.
// ---------------------------------------------------------------------------
__global__ __launch_bounds__(256) void hwcv_kernel(const float* __restrict__ H,
                                                   const float* __restrict__ W,
                                                   const float* __restrict__ Cv,
                                                   float* __restrict__ hw,
                                                   bf16_t* __restrict__ Cvb) {
    int wave = threadIdx.x >> 6;
    int lane = threadIdx.x & 63;
    if (blockIdx.x < (B_ * T_ / 4)) {
        long row = (long)blockIdx.x * 4 + wave;          // [0, B*T)
        const float* h = H + row * D_;
        float acc = 0.f;
        if (lane < 50) {
            const float4* p  = (const float4*)(h + lane * 8);
            const float4* wp = (const float4*)(W + lane * 8);
            float4 x = p[0], y = p[1];
            acc = dot4(x, wp[0]) + dot4(y, wp[1]);
        }
#pragma unroll
        for (int off = 1; off < 64; off <<= 1) acc += __shfl_xor(acc, off, 64);
        if (lane == 0) hw[row] = acc;
    } else {
        int row = (blockIdx.x - (B_ * T_ / 4)) * 4 + wave;   // [0, NV)
        const float* src = Cv + (size_t)row * D_;
        bf16_t* dst = Cvb + (size_t)row * LDH;
        if (lane < 50) {
            const float4* p = (const float4*)(src + lane * 8);
            float4 x = p[0], y = p[1];
            bf16x8 f;
            f[0] = (bf16_t)x.x; f[1] = (bf16_t)x.y; f[2] = (bf16_t)x.z; f[3] = (bf16_t)x.w;
            f[4] = (bf16_t)y.x; f[5] = (bf16_t)y.y; f[6] = (bf16_t)y.z; f[7] = (bf16_t)y.w;
            *(bf16x8*)(dst + lane * 8) = f;
        } else if (lane < 52) {
            bf16x8 z;
#pragma unroll
            for (int j = 0; j < 8; ++j) z[j] = (bf16_t)0.0f;
            *(bf16x8*)(dst + lane * 8) = z;              // pad 400..415
        }
    }
}

// ---------------------------------------------------------------------------
// Kernel 2 (FUSED s2 + qacts): block per b.  (unchanged, verified)
// ---------------------------------------------------------------------------
__global__ __launch_bounds__(256) void qacts_kernel(const float* __restrict__ cu,
                                                    const float* __restrict__ Ca,
                                                    float* __restrict__ q_ws) {
    __shared__ __align__(16) float4 cu4[100];
    __shared__ float s_lds[NA];
    __shared__ float p_lds[NA];
    __shared__ float red[8];
    __shared__ __align__(16) float4 part[100];
    int b = blockIdx.x;
    int tid = threadIdx.x, wave = tid >> 6, lane = tid & 63;

    if (tid < 100) cu4[tid] = ((const float4*)(cu + (size_t)b * D_))[tid];
    __syncthreads();

    const float4* Cb4 = (const float4*)(Ca + (size_t)b * NA * D_);
#pragma unroll 2
    for (int i = 0; i < 32; ++i) {
        int a = wave * 32 + i;
        const float4* row = Cb4 + (size_t)a * 100;
        float acc = dot4(row[lane], cu4[lane]);
        if (lane < 36) acc += dot4(row[lane + 64], cu4[lane + 64]);
#pragma unroll
        for (int off = 1; off < 64; off <<= 1) acc += __shfl_xor(acc, off, 64);
        if (lane == 0) s_lds[a] = acc;
    }
    __syncthreads();

    float s = (tid < NA) ? s_lds[tid] : -3.0e38f;
    float m = s;
#pragma unroll
    for (int off = 1; off < 64; off <<= 1) m = fmaxf(m, __shfl_xor(m, off, 64));
    if (lane == 0) red[wave] = m;
    __syncthreads();
    m = fmaxf(red[0], red[1]);
    float e = (tid < NA) ? __expf(s - m) : 0.f;
    float sum = e;
#pragma unroll
    for (int off = 1; off < 64; off <<= 1) sum += __shfl_xor(sum, off, 64);
    if (lane == 0) red[4 + wave] = sum;
    __syncthreads();
    float S = red[4] + red[5];
    if (tid < NA) p_lds[tid] = e / S;
    __syncthreads();

    int c4 = tid % 100;
    int half = tid / 100;
    float4 acc0 = {0.f, 0.f, 0.f, 0.f};
    if (tid < 200) {
        float4 acc1 = {0.f, 0.f, 0.f, 0.f};
        int a0 = half * 64;
#pragma unroll 4
        for (int a = 0; a < 64; a += 2) {
            float p0 = p_lds[a0 + a], p1 = p_lds[a0 + a + 1];
            float4 x0 = Cb4[(size_t)(a0 + a) * 100 + c4];
            float4 x1 = Cb4[(size_t)(a0 + a + 1) * 100 + c4];
            acc0.x += p0 * x0.x; acc0.y += p0 * x0.y; acc0.z += p0 * x0.z; acc0.w += p0 * x0.w;
            acc1.x += p1 * x1.x; acc1.y += p1 * x1.y; acc1.z += p1 * x1.z; acc1.w += p1 * x1.w;
        }
        acc0.x += acc1.x; acc0.y += acc1.y; acc0.z += acc1.z; acc0.w += acc1.w;
        if (half == 1) part[c4] = acc0;
    }
    __syncthreads();
    if (tid < 100) {
        float4 o = part[c4];
        o.x += acc0.x; o.y += acc0.y; o.z += acc0.z; o.w += acc0.w;
        ((float4*)(q_ws + (size_t)b * D_))[c4] = o;
    }
}

// ---------------------------------------------------------------------------
// Kernel 3 (main): block = (b, chunk). Stage 64xD H-chunk once (f32 -> bf16,
// swizzled ds_write), then barrier-free v-loop producing per-chunk (m,l,a)[v].
// ---------------------------------------------------------------------------
__global__ __launch_bounds__(256, 3) void main_kernel(const float* __restrict__ H,
                                                      const bf16_t* __restrict__ Cvb,
                                                      const float* __restrict__ hw,
                                                      const int* __restrict__ lens,
                                                      float* __restrict__ mws,
                                                      float* __restrict__ lws,
                                                      float* __restrict__ aws) {
    __shared__ bf16_t h_lds[NT * LDH];   // 53248 B -> 3 blocks/CU

    int i = blockIdx.x;
    int b = i >> 3, ch = i & 7;
    int t0 = ch * NT;
    int tid = threadIdx.x;
    int wave = tid >> 6, lane = tid & 63;
    int lrow = lane & 15, quad = lane >> 4;
    int len = lens[b];
    size_t obase = ((size_t)b * NCH + ch) * NV;

    if (t0 >= len) {
        // empty chunk: write neutral merge triple for all 1024 v and exit
        floatx4 m4 = {-3.0e38f, -3.0e38f, -3.0e38f, -3.0e38f};
        floatx4 z4 = {0.f, 0.f, 0.f, 0.f};
        *(floatx4*)(mws + obase + tid * 4) = m4;
        *(floatx4*)(lws + obase + tid * 4) = z4;
        *(floatx4*)(aws + obase + tid * 4) = z4;
        return;
    }

    // zero pad chunks 50,51 of each row
    if (tid < 128) {
        int r = tid >> 1, c = 50 + (tid & 1);
        bf16x8 z;
#pragma unroll
        for (int j = 0; j < 8; ++j) z[j] = (bf16_t)0.0f;
        *(bf16x8*)((char*)h_lds + r * 832 + c * 16) = z;
    }

    // stage: 64 rows x 50 chunks, swizzled
    const float* Hb = H + ((size_t)b * T_ + t0) * D_;
    for (int idx = tid; idx < NT * 50; idx += 256) {
        int r = idx / 50, c = idx - r * 50;
        const float4* s = (const float4*)(Hb + (size_t)r * D_ + c * 8);
        float4 x = s[0], y = s[1];
        bf16x8 f;
        f[0] = (bf16_t)x.x; f[1] = (bf16_t)x.y; f[2] = (bf16_t)x.z; f[3] = (bf16_t)x.w;
        f[4] = (bf16_t)y.x; f[5] = (bf16_t)y.y; f[6] = (bf16_t)y.z; f[7] = (bf16_t)y.w;
        int pos = (c < 48) ? (c ^ (r & 7)) : c;
        *(bf16x8*)((char*)h_lds + r * 832 + pos * 16) = f;
    }
    __syncthreads();
    // ---- no further barriers: waves run independent v-loops ----

    const float* hwb = hw + (size_t)b * T_ + t0;
    float hwv[4], mb[4];
    bool partial = (t0 + NT > len);
#pragma unroll
    for (int ts = 0; ts < 4; ++ts) {
        int t = ts * 16 + lrow;
        hwv[ts] = hwb[t];
        mb[ts] = (t0 + t < len) ? 0.f : -3.0e38f;
    }
    const int swz = (lrow & 7) << 4;
    int rowb[4];
#pragma unroll
    for (int ts = 0; ts < 4; ++ts) rowb[ts] = (ts * 16 + lrow) * 832;

    for (int it = 0; it < 4; ++it) {
        int vb = it * 256 + wave * 64;
        const bf16_t* abase[4];
#pragma unroll
        for (int s = 0; s < 4; ++s)
            abase[s] = Cvb + (size_t)(vb + s * 16 + lrow) * LDH + quad * 8;

        floatx4 c[4][4];
        floatx4 zero4 = {0.f, 0.f, 0.f, 0.f};
#pragma unroll
        for (int s = 0; s < 4; ++s)
#pragma unroll
            for (int ts = 0; ts < 4; ++ts) c[s][ts] = zero4;

#pragma unroll
        for (int kk = 0; kk < 13; ++kk) {
            bf16x8 a[4];
#pragma unroll
            for (int s = 0; s < 4; ++s) a[s] = *(const bf16x8*)(abase[s] + kk * 32);
            int koffb = kk * 64 + quad * 16;
            int o = (kk < 12) ? (koffb ^ swz) : koffb;   // chunks 48-51 raw
            bf16x8 bf[4];
#pragma unroll
            for (int ts = 0; ts < 4; ++ts)
                bf[ts] = *(const bf16x8*)((char*)h_lds + rowb[ts] + o);
#pragma unroll
            for (int s = 0; s < 4; ++s)
#pragma unroll
                for (int ts = 0; ts < 4; ++ts)
                    c[s][ts] = __builtin_amdgcn_mfma_f32_16x16x32_bf16(a[s], bf[ts], c[s][ts], 0, 0, 0);
        }

        if (partial) {
#pragma unroll
            for (int s = 0; s < 4; ++s)
#pragma unroll
                for (int ts = 0; ts < 4; ++ts)
#pragma unroll
                    for (int r = 0; r < 4; ++r) c[s][ts][r] += mb[ts];
        }

#pragma unroll
        for (int s = 0; s < 4; ++s) {
            floatx4 mo, lo, ao;
#pragma unroll
            for (int r = 0; r < 4; ++r) {
                float m = fmaxf(fmaxf(c[s][0][r], c[s][1][r]),
                                fmaxf(c[s][2][r], c[s][3][r]));
#pragma unroll
                for (int off = 1; off < 16; off <<= 1) m = fmaxf(m, __shfl_xor(m, off, 64));
                float ps = 0.f, qs = 0.f;
#pragma unroll
                for (int ts = 0; ts < 4; ++ts) {
                    float p = __expf(c[s][ts][r] - m);
                    ps += p;
                    qs += p * hwv[ts];
                }
#pragma unroll
                for (int off = 1; off < 16; off <<= 1) {
                    ps += __shfl_xor(ps, off, 64);
                    qs += __shfl_xor(qs, off, 64);
                }
                mo[r] = m; lo[r] = ps; ao[r] = qs;
            }
            if (lrow == 0) {
                size_t o2 = obase + vb + s * 16 + quad * 4;
                *(floatx4*)(mws + o2) = mo;
                *(floatx4*)(lws + o2) = lo;
                *(floatx4*)(aws + o2) = ao;
            }
        }
    }
}

// ---------------------------------------------------------------------------
// Kernel 4 (combine): merge 8 chunk-triples -> y_utts; then y_acts (f32 dots).
// Block = (b, vgroup of 256). 512 blocks x 256 threads.
// ---------------------------------------------------------------------------
__global__ __launch_bounds__(256) void combine_kernel(const float* __restrict__ mws,
                                                      const float* __restrict__ lws,
                                                      const float* __restrict__ aws,
                                                      const float* __restrict__ q_ws,
                                                      const float* __restrict__ Cv,
                                                      const float* __restrict__ bs,
                                                      float* __restrict__ out) {
    int bid = blockIdx.x;
    int b = bid >> 2, vg = bid & 3;
    int tid = threadIdx.x;
    int v = vg * 256 + tid;

    // y_utts merge
    size_t base = ((size_t)b * NCH) * NV + v;
    float mv[NCH];
    float M = -3.0e38f;
#pragma unroll
    for (int c = 0; c < NCH; ++c) {
        mv[c] = mws[base + (size_t)c * NV];
        M = fmaxf(M, mv[c]);
    }
    float lt = 0.f, at = 0.f;
#pragma unroll
    for (int c = 0; c < NCH; ++c) {
        float f = __expf(mv[c] - M);
        lt += lws[base + (size_t)c * NV] * f;
        at += aws[base + (size_t)c * NV] * f;
    }
    out[(size_t)b * NV + v] = at / lt + bs[0];

    // y_acts: wave per 64 v (f32, precision parity with prior yacts kernel)
    int wave = tid >> 6, lane = tid & 63;
    const float4* q4 = (const float4*)(q_ws + (size_t)b * D_);
    float4 qa = q4[lane];
    float4 qb = (lane < 36) ? q4[lane + 64] : make_float4(0.f, 0.f, 0.f, 0.f);
    int v0base = vg * 256 + wave * 64;
#pragma unroll 1
    for (int ii = 0; ii < 64; ii += 4) {
        int v0 = v0base + ii;
        float acc[4];
#pragma unroll
        for (int r = 0; r < 4; ++r) {
            const float4* v4 = (const float4*)(Cv + (size_t)(v0 + r) * D_);
            acc[r] = dot4(v4[lane], qa);
            if (lane < 36) acc[r] += dot4(v4[lane + 64], qb);
        }
#pragma unroll
        for (int off = 1; off < 64; off <<= 1) {
#pragma unroll
            for (int r = 0; r < 4; ++r) acc[r] += __shfl_xor(acc[r], off, 64);
        }
        if (lane == 0) {
            float4 o = make_float4(acc[0], acc[1], acc[2], acc[3]);
            *(float4*)(out + (size_t)B_ * NV + (size_t)b * NV + v0) = o;
        }
    }
}

// ---------------------------------------------------------------------------
extern "C" void kernel_launch(void* const* d_in, const int* in_sizes, int n_in,
                              void* d_out, int out_size, void* d_ws, size_t ws_size,
                              hipStream_t stream) {
    const float* H    = (const float*)d_in[0];   // (B,T,D)
    const float* cu   = (const float*)d_in[1];   // (B,D)
    const float* Ca   = (const float*)d_in[2];   // (B,NA,D)
    const float* Cv   = (const float*)d_in[3];   // (NV,1,D)
    const float* W    = (const float*)d_in[4];   // (1,D)
    const float* bs   = (const float*)d_in[5];   // (1,)
    const int*   lens = (const int*)d_in[6];     // (B,)
    float* out = (float*)d_out;                  // f32: y_utts (B,NV) ++ y_acts (B,NV)

    // workspace layout (~13.6 MB total)
    float*  hw   = (float*)d_ws;                         // B*T f32      (256 KB)
    float*  q_ws = hw + (size_t)B_ * T_;                 // B*D f32      (200 KB)
    bf16_t* Cvb  = (bf16_t*)(q_ws + (size_t)B_ * D_);    // NV*416 bf16  (832 KB)
    float*  mws  = (float*)(Cvb + (size_t)NV * LDH);     // B*8*NV f32   (4 MB)
    float*  lws  = mws + (size_t)B_ * NCH * NV;          // 4 MB
    float*  aws  = lws + (size_t)B_ * NCH * NV;          // 4 MB

    hwcv_kernel<<<dim3(B_ * T_ / 4 + NV / 4), dim3(256), 0, stream>>>(H, W, Cv, hw, Cvb);
    qacts_kernel<<<dim3(B_), dim3(256), 0, stream>>>(cu, Ca, q_ws);
    main_kernel<<<dim3(B_ * NCH), dim3(256), 0, stream>>>(H, Cvb, hw, lens, mws, lws, aws);
    combine_kernel<<<dim3(B_ * 4), dim3(256), 0, stream>>>(mws, lws, aws, q_ws, Cv, bs, out);
}

// Round 4
// 312.071 us; speedup vs baseline: 1.6170x; 1.6170x over previous
//
#include <hip/hip_runtime.h>
#include <hip/hip_bf16.h>

// Problem constants
#define B_  128
#define T_  512
#define D_  400
#define NV  1024
#define NA  128

// Main-kernel tiling (round-1 dataflow + T3/T4 pipeline):
//   block = (b, v-chunk of 128); wave owns 32 v (2 sets of 16) stationary in regs.
//   H tiles of NT=32 rows stream through THREE LDS buffers; raw s_barrier +
//   counted vmcnt(14) keeps 2 tiles of prefetch in flight across barriers.
// LDH=416 (832 B rows), swizzle: 16B chunk c of row r at c ^ (r&7) for c<48
// (numerics verified rounds 2-3). Buffer = 32*832 = 26624 B; 3 bufs + 2 KB hw
// = 81920 B = 80 KB exactly -> 2 blocks/CU.
#define LDH   416
#define NT    32
#define TILEB (NT * LDH * 2)        // 26624 bytes per buffer
#define CHUNKS_PER_TILE (TILEB/16)  // 1664; 416 per wave; 7 issues/wave (uniform)
#define MV    128

typedef __bf16 bf16_t;
typedef bf16_t bf16x8 __attribute__((ext_vector_type(8)));
typedef float  floatx4 __attribute__((ext_vector_type(4)));

__device__ inline void async_copy16(const void* g, void* l) {
    __builtin_amdgcn_global_load_lds(
        (const __attribute__((address_space(1))) unsigned int*)g,
        (__attribute__((address_space(3))) unsigned int*)l, 16, 0, 0);
}

__device__ inline float dot4(float4 a, float4 b) {
    return a.x * b.x + a.y * b.y + a.z * b.z + a.w * b.w;
}

// ---------------------------------------------------------------------------
// prep kernel: blocks [0, B*T/4): hw[b,t] = H row . W  AND swizzled bf16 Hbf row.
//              blocks [B*T/4, +B): fused s2+qacts for b = blockIdx - B*T/4.
// ---------------------------------------------------------------------------
template<int PRE>
__global__ __launch_bounds__(256) void prep_kernel(const float* __restrict__ H,
                                                   const float* __restrict__ W,
                                                   const float* __restrict__ cu,
                                                   const float* __restrict__ Ca,
                                                   float* __restrict__ hw,
                                                   bf16_t* __restrict__ Hbf,
                                                   float* __restrict__ q_ws) {
    __shared__ __align__(16) float4 cu4[100];
    __shared__ float s_lds[NA];
    __shared__ float p_lds[NA];
    __shared__ float red[8];
    __shared__ __align__(16) float4 part[100];

    int tid = threadIdx.x, wave = tid >> 6, lane = tid & 63;

    if (blockIdx.x < (B_ * T_ / 4)) {
        // ---- hw + Hbf ----
        long row = (long)blockIdx.x * 4 + wave;          // [0, B*T)
        int key = (int)(row & 7);
        const float* h = H + row * D_;
        float acc = 0.f;
        if (lane < 50) {
            const float4* p  = (const float4*)(h + lane * 8);
            const float4* wp = (const float4*)(W + lane * 8);
            float4 x = p[0], y = p[1];
            acc = dot4(x, wp[0]) + dot4(y, wp[1]);
            if (PRE) {
                bf16x8 f;
                f[0] = (bf16_t)x.x; f[1] = (bf16_t)x.y; f[2] = (bf16_t)x.z; f[3] = (bf16_t)x.w;
                f[4] = (bf16_t)y.x; f[5] = (bf16_t)y.y; f[6] = (bf16_t)y.z; f[7] = (bf16_t)y.w;
                int pos = (lane < 48) ? (lane ^ key) : lane;
                *(bf16x8*)(Hbf + row * (long)LDH + pos * 8) = f;
            }
        } else if (PRE && lane < 52) {
            bf16x8 z;
#pragma unroll
            for (int j = 0; j < 8; ++j) z[j] = (bf16_t)0.0f;
            *(bf16x8*)(Hbf + row * (long)LDH + lane * 8) = z;    // pad chunks 50,51
        }
#pragma unroll
        for (int off = 1; off < 64; off <<= 1) acc += __shfl_xor(acc, off, 64);
        if (lane == 0) hw[row] = acc;
        return;
    }

    // ---- fused s2 + qacts (block-uniform branch; barriers OK) ----
    int b = blockIdx.x - (B_ * T_ / 4);

    if (tid < 100) cu4[tid] = ((const float4*)(cu + (size_t)b * D_))[tid];
    __syncthreads();

    const float4* Cb4 = (const float4*)(Ca + (size_t)b * NA * D_);
#pragma unroll 2
    for (int i = 0; i < 32; ++i) {
        int a = wave * 32 + i;
        const float4* row = Cb4 + (size_t)a * 100;
        float acc = dot4(row[lane], cu4[lane]);
        if (lane < 36) acc += dot4(row[lane + 64], cu4[lane + 64]);
#pragma unroll
        for (int off = 1; off < 64; off <<= 1) acc += __shfl_xor(acc, off, 64);
        if (lane == 0) s_lds[a] = acc;
    }
    __syncthreads();

    float s = (tid < NA) ? s_lds[tid] : -3.0e38f;
    float m = s;
#pragma unroll
    for (int off = 1; off < 64; off <<= 1) m = fmaxf(m, __shfl_xor(m, off, 64));
    if (lane == 0) red[wave] = m;
    __syncthreads();
    m = fmaxf(red[0], red[1]);
    float e = (tid < NA) ? __expf(s - m) : 0.f;
    float sum = e;
#pragma unroll
    for (int off = 1; off < 64; off <<= 1) sum += __shfl_xor(sum, off, 64);
    if (lane == 0) red[4 + wave] = sum;
    __syncthreads();
    float S = red[4] + red[5];
    if (tid < NA) p_lds[tid] = e / S;
    __syncthreads();

    int c4 = tid % 100;
    int half = tid / 100;
    float4 acc0 = {0.f, 0.f, 0.f, 0.f};
    if (tid < 200) {
        float4 acc1 = {0.f, 0.f, 0.f, 0.f};
        int a0 = half * 64;
#pragma unroll 4
        for (int a = 0; a < 64; a += 2) {
            float p0 = p_lds[a0 + a], p1 = p_lds[a0 + a + 1];
            float4 x0 = Cb4[(size_t)(a0 + a) * 100 + c4];
            float4 x1 = Cb4[(size_t)(a0 + a + 1) * 100 + c4];
            acc0.x += p0 * x0.x; acc0.y += p0 * x0.y; acc0.z += p0 * x0.z; acc0.w += p0 * x0.w;
            acc1.x += p1 * x1.x; acc1.y += p1 * x1.y; acc1.z += p1 * x1.z; acc1.w += p1 * x1.w;
        }
        acc0.x += acc1.x; acc0.y += acc1.y; acc0.z += acc1.z; acc0.w += acc1.w;
        if (half == 1) part[c4] = acc0;
    }
    __syncthreads();
    if (tid < 100) {
        float4 o = part[c4];
        o.x += acc0.x; o.y += acc0.y; o.z += acc0.z; o.w += acc0.w;
        ((float4*)(q_ws + (size_t)b * D_))[c4] = o;
    }
}

// ---------------------------------------------------------------------------
// Main kernel: round-1 dataflow + 3-buffer counted-vmcnt pipeline (PRE=1).
// ---------------------------------------------------------------------------
template<int PRE>
__global__ __launch_bounds__(256, 2) void main_kernel(const float* __restrict__ H,
                                                      const bf16_t* __restrict__ Hbf,
                                                      const float* __restrict__ Cv,
                                                      const float* __restrict__ hw,
                                                      const float* __restrict__ q_ws,
                                                      const float* __restrict__ bs,
                                                      const int* __restrict__ lens,
                                                      float* __restrict__ out) {
    __shared__ __align__(16) char lds_raw[3 * TILEB + 2048];   // 81920 B = 80 KB
    char* Lbuf = lds_raw;
    float* hw_f = (float*)(lds_raw + 3 * TILEB);               // 512 floats

    int i = blockIdx.x;
    int xcd = i & 7, vc = (i >> 3) & 7, bb = i >> 6;
    int b = xcd + 8 * bb;            // all 8 v-chunks of b land on one XCD
    int vbase = vc * MV;

    int tid = threadIdx.x;
    int wave = tid >> 6, lane = tid & 63;
    int lrow = lane & 15, quad = lane >> 4;

    int len = lens[b];
    float b0 = bs[0];
    int ntiles = (len + NT - 1) / NT;     // uniform per block; >= 8

    const float* Hb = H + (size_t)b * T_ * D_;
    const bf16_t* Hbfb = Hbf + (size_t)b * T_ * LDH;
    const float* hwb = hw + (size_t)b * T_;

    // --- A fragments: this wave's 32 Cv rows, stationary (as round 1) ---
    bf16x8 afrag[2][13];
#pragma unroll
    for (int set = 0; set < 2; ++set) {
        const float* vrow = Cv + (size_t)(vbase + wave * 32 + set * 16 + lrow) * D_;
#pragma unroll
        for (int kk = 0; kk < 13; ++kk) {
            int k0 = kk * 32 + quad * 8;
            bf16x8 f;
            if (k0 >= D_) {
#pragma unroll
                for (int j = 0; j < 8; ++j) f[j] = (bf16_t)0.0f;
            } else {
                const float4* p = (const float4*)(vrow + k0);
                float4 x = p[0], y = p[1];
                f[0] = (bf16_t)x.x; f[1] = (bf16_t)x.y;
                f[2] = (bf16_t)x.z; f[3] = (bf16_t)x.w;
                f[4] = (bf16_t)y.x; f[5] = (bf16_t)y.y;
                f[6] = (bf16_t)y.z; f[7] = (bf16_t)y.w;
            }
            afrag[set][kk] = f;
        }
    }

    float m_s[2][4], l_s[2][4], a_s[2][4];
#pragma unroll
    for (int set = 0; set < 2; ++set)
#pragma unroll
        for (int r = 0; r < 4; ++r) { m_s[set][r] = -3.0e38f; l_s[set][r] = 0.f; a_s[set][r] = 0.f; }

    // stage: exactly 7 global_load_lds per wave (uniform -> sound vmcnt counting).
    // wave w owns chunks [w*416, (w+1)*416); lane l does c = w*416 + l + 64k.
    auto stage = [&](int loff, int tt) {
        const char* gt = (const char*)(Hbfb + (size_t)tt * NT * LDH);
        char* lt = Lbuf + loff;
        int cbase = wave * 416 + lane;
#pragma unroll
        for (int k = 0; k < 7; ++k) {
            int c = cbase + (k << 6);
            if (lane + (k << 6) < 416)
                async_copy16(gt + c * 16, lt + c * 16);
        }
    };

    // PRE=0 fallback staging: reg-stage f32 -> bf16 with swizzled ds_write.
    auto stage_f32 = [&](int loff, int tt) {
        for (int idx = tid; idx < NT * 50; idx += 256) {
            int r = idx / 50, c = idx - r * 50;
            const float4* s = (const float4*)(Hb + (size_t)(tt * NT + r) * D_ + c * 8);
            float4 x = s[0], y = s[1];
            bf16x8 f;
            f[0] = (bf16_t)x.x; f[1] = (bf16_t)x.y; f[2] = (bf16_t)x.z; f[3] = (bf16_t)x.w;
            f[4] = (bf16_t)y.x; f[5] = (bf16_t)y.y; f[6] = (bf16_t)y.z; f[7] = (bf16_t)y.w;
            int pos = (c < 48) ? (c ^ (r & 7)) : c;
            *(bf16x8*)(Lbuf + loff + r * 832 + pos * 16) = f;
        }
    };

    int o0 = 0, o1 = TILEB, o2 = 2 * TILEB;   // rotating buffer offsets

    // ---- prologue ----
    if (PRE) {
        if (tid < 128) async_copy16((const char*)hwb + tid * 16, (char*)hw_f + tid * 16);
        asm volatile("s_waitcnt vmcnt(0)" ::: "memory");   // hw_f landed
        stage(o0, 0);
        stage(o1, 1);
        __builtin_amdgcn_s_barrier();                      // hw_f visible to all
    } else {
        if (tid < 256) ((float2*)hw_f)[tid] = ((const float2*)hwb)[tid];
        // zero pad chunks 50,51 of each row in all 3 buffers
        for (int idx = tid; idx < 3 * NT * 2; idx += 256) {
            int bu = idx / (NT * 2), rem = idx % (NT * 2);
            int r = rem >> 1, c = 50 + (rem & 1);
            bf16x8 z;
#pragma unroll
            for (int j = 0; j < 8; ++j) z[j] = (bf16_t)0.0f;
            *(bf16x8*)(Lbuf + bu * TILEB + r * 832 + c * 16) = z;
        }
        __syncthreads();
    }

    const int swz = (lrow & 7) << 4;
    const int rowb0 = lrow * 832;
    const int rowb1 = (16 + lrow) * 832;

    for (int tt = 0; tt < ntiles; ++tt) {
        if (PRE) {
            asm volatile("s_waitcnt lgkmcnt(0)" ::: "memory");
            __builtin_amdgcn_s_barrier();                  // all waves done with o2's old tile
            if (tt + 2 < ntiles) {
                stage(o2, tt + 2);                         // prefetch depth 2
                asm volatile("s_waitcnt vmcnt(14)" ::: "memory");   // tile tt landed
            } else if (tt + 1 < ntiles) {
                asm volatile("s_waitcnt vmcnt(7)" ::: "memory");
            } else {
                asm volatile("s_waitcnt vmcnt(0)" ::: "memory");
            }
            __builtin_amdgcn_sched_barrier(0);
        } else {
            __syncthreads();
            stage_f32(o0, tt);
            __syncthreads();
        }

        int t0 = tt * NT;
        float hwv[2];
#pragma unroll
        for (int s = 0; s < 2; ++s) hwv[s] = hw_f[t0 + s * 16 + lrow];

        floatx4 c[2][2];
        floatx4 zero4 = {0.f, 0.f, 0.f, 0.f};
#pragma unroll
        for (int set = 0; set < 2; ++set)
#pragma unroll
            for (int s = 0; s < 2; ++s) c[set][s] = zero4;

        const char* L = (const char*)(Lbuf + o0);
#pragma unroll
        for (int kk = 0; kk < 13; ++kk) {
            int koffb = kk * 64 + quad * 16;
            int o = (kk < 12) ? (koffb ^ swz) : koffb;     // chunks 48-51 raw
            bf16x8 f0 = *(const bf16x8*)(L + rowb0 + o);
            c[0][0] = __builtin_amdgcn_mfma_f32_16x16x32_bf16(afrag[0][kk], f0, c[0][0], 0, 0, 0);
            c[1][0] = __builtin_amdgcn_mfma_f32_16x16x32_bf16(afrag[1][kk], f0, c[1][0], 0, 0, 0);
            bf16x8 f1 = *(const bf16x8*)(L + rowb1 + o);
            c[0][1] = __builtin_amdgcn_mfma_f32_16x16x32_bf16(afrag[0][kk], f1, c[0][1], 0, 0, 0);
            c[1][1] = __builtin_amdgcn_mfma_f32_16x16x32_bf16(afrag[1][kk], f1, c[1][1], 0, 0, 0);
        }

        if (t0 + NT > len) {
#pragma unroll
            for (int s = 0; s < 2; ++s) {
                int t = t0 + s * 16 + lrow;
                if (t >= len) {
#pragma unroll
                    for (int set = 0; set < 2; ++set) {
                        c[set][s][0] = -3.0e38f; c[set][s][1] = -3.0e38f;
                        c[set][s][2] = -3.0e38f; c[set][s][3] = -3.0e38f;
                    }
                }
            }
        }

#pragma unroll
        for (int set = 0; set < 2; ++set)
#pragma unroll
            for (int r = 0; r < 4; ++r) {
                float cm = fmaxf(c[set][0][r], c[set][1][r]);
                float mn = fmaxf(m_s[set][r], cm);
                float alpha = __expf(m_s[set][r] - mn);
                float ps = 0.f, qs = 0.f;
#pragma unroll
                for (int s = 0; s < 2; ++s) {
                    float p = __expf(c[set][s][r] - mn);
                    ps += p;
                    qs += p * hwv[s];
                }
                l_s[set][r] = l_s[set][r] * alpha + ps;
                a_s[set][r] = a_s[set][r] * alpha + qs;
                m_s[set][r] = mn;
            }

        int tmp = o0; o0 = o1; o1 = o2; o2 = tmp;          // rotate buffers
    }

    // y_utts reduce + write
#pragma unroll
    for (int set = 0; set < 2; ++set)
#pragma unroll
        for (int r = 0; r < 4; ++r) {
            float m = m_s[set][r], l = l_s[set][r], a = a_s[set][r];
#pragma unroll
            for (int off = 1; off < 16; off <<= 1) {
                float mo = __shfl_xor(m, off, 64);
                float lo = __shfl_xor(l, off, 64);
                float ao = __shfl_xor(a, off, 64);
                float mn = fmaxf(m, mo);
                float f1 = __expf(m - mn), f2 = __expf(mo - mn);
                l = l * f1 + lo * f2;
                a = a * f1 + ao * f2;
                m = mn;
            }
            if (lrow == 0) {
                int v = vbase + wave * 32 + set * 16 + quad * 4 + r;
                out[(size_t)b * NV + v] = a / l + b0;
            }
        }

    // y_acts epilogue: this block owns (b, vbase..vbase+127)
    {
        const float4* q4 = (const float4*)(q_ws + (size_t)b * D_);
        float4 qa = q4[lane];
        float4 qb = (lane < 36) ? q4[lane + 64] : make_float4(0.f, 0.f, 0.f, 0.f);
#pragma unroll 1
        for (int ii = 0; ii < 32; ii += 4) {
            int v0 = vbase + wave * 32 + ii;
            float acc[4];
#pragma unroll
            for (int r = 0; r < 4; ++r) {
                const float4* v4 = (const float4*)(Cv + (size_t)(v0 + r) * D_);
                acc[r] = dot4(v4[lane], qa);
                if (lane < 36) acc[r] += dot4(v4[lane + 64], qb);
            }
#pragma unroll
            for (int off = 1; off < 64; off <<= 1) {
#pragma unroll
                for (int r = 0; r < 4; ++r) acc[r] += __shfl_xor(acc[r], off, 64);
            }
            if (lane == 0) {
                float4 o = make_float4(acc[0], acc[1], acc[2], acc[3]);
                *(float4*)(out + (size_t)B_ * NV + (size_t)b * NV + v0) = o;
            }
        }
    }
}

// ---------------------------------------------------------------------------
extern "C" void kernel_launch(void* const* d_in, const int* in_sizes, int n_in,
                              void* d_out, int out_size, void* d_ws, size_t ws_size,
                              hipStream_t stream) {
    const float* H    = (const float*)d_in[0];   // (B,T,D)
    const float* cu   = (const float*)d_in[1];   // (B,D)
    const float* Ca   = (const float*)d_in[2];   // (B,NA,D)
    const float* Cv   = (const float*)d_in[3];   // (NV,1,D)
    const float* W    = (const float*)d_in[4];   // (1,D)
    const float* bs   = (const float*)d_in[5];   // (1,)
    const int*   lens = (const int*)d_in[6];     // (B,)
    float* out = (float*)d_out;                  // f32: y_utts (B,NV) ++ y_acts (B,NV)

    float*  hw   = (float*)d_ws;                        // B*T f32 (256 KB)
    float*  q_ws = hw + (size_t)B_ * T_;                // B*D f32 (200 KB)
    bf16_t* Hbf  = (bf16_t*)(q_ws + (size_t)B_ * D_);   // B*T*416 bf16 (54.5 MB)

    size_t need = ((size_t)B_ * T_ + (size_t)B_ * D_) * sizeof(float)
                + (size_t)B_ * T_ * LDH * sizeof(bf16_t);
    bool pre = (ws_size >= need);

    dim3 pgrid(B_ * T_ / 4 + B_);
    if (pre) {
        prep_kernel<1><<<pgrid, dim3(256), 0, stream>>>(H, W, cu, Ca, hw, Hbf, q_ws);
        main_kernel<1><<<dim3(1024), dim3(256), 0, stream>>>(H, Hbf, Cv, hw, q_ws, bs, lens, out);
    } else {
        prep_kernel<0><<<pgrid, dim3(256), 0, stream>>>(H, W, cu, Ca, hw, Hbf, q_ws);
        main_kernel<0><<<dim3(1024), dim3(256), 0, stream>>>(H, Hbf, Cv, hw, q_ws, bs, lens, out);
    }
}